// Round 5
// baseline (2853.557 us; speedup 1.0000x reference)
//
#include <hip/hip_runtime.h>

#define BATCH   4
#define NPTS    8192
#define NPOINT  2048
#define NSAMPLE 32
#define NCH     67
#define NOUT    128
#define NP      4      // centers per conv block
#define FPS_T   256
#define NWAVE   (FPS_T / 64)     // 4 waves
#define KPT     (NPTS / FPS_T)   // 32 points per thread (setup passes)

// DPP ctrl encodings (gfx9/CDNA)
#define DPP_ROW_SHR1    0x111
#define DPP_ROW_SHR2    0x112
#define DPP_ROW_SHR4    0x114
#define DPP_ROW_SHR8    0x118
#define DPP_ROW_BCAST15 0x142
#define DPP_ROW_BCAST31 0x143

// max-combine one DPP hop on a packed u64 key. bound_ctrl=1 zero-fills edge
// lanes; 0 is a safe identity (a 0 key can never win the global argmax since
// some point always has dist > 0).
#define DPP_MAX_HOP(key, ctrl)                                                 \
    {                                                                          \
        int _lo = (int)(unsigned)(key);                                        \
        int _hi = (int)(unsigned)((key) >> 32);                                \
        int _olo = __builtin_amdgcn_update_dpp(0, _lo, (ctrl), 0xF, 0xF, true);\
        int _ohi = __builtin_amdgcn_update_dpp(0, _hi, (ctrl), 0xF, 0xF, true);\
        unsigned long long _o =                                                \
            ((unsigned long long)(unsigned)_ohi << 32) | (unsigned)_olo;       \
        if (_o > (key)) (key) = _o;                                            \
    }

#define DPP_REDUCE_MAX(key)            \
    DPP_MAX_HOP(key, DPP_ROW_SHR1);    \
    DPP_MAX_HOP(key, DPP_ROW_SHR2);    \
    DPP_MAX_HOP(key, DPP_ROW_SHR4);    \
    DPP_MAX_HOP(key, DPP_ROW_SHR8);    \
    DPP_MAX_HOP(key, DPP_ROW_BCAST15); \
    DPP_MAX_HOP(key, DPP_ROW_BCAST31);

// ---------------------------------------------------------------------------
// Bucketed FPS, one block/batch, 256 threads. Points counting-sorted into
// 256 spatial cells (8x8x4) living in LDS as float4(x,y,z,dist). A bucket
// whose box is provably too far from the new center (dmin2 >= ub*(1+m)) is
// skipped: no dist in it can change (d >= dmin >= ub >= dist), and its cached
// argmax key stays valid. Scanned buckets go through a compact wave work
// queue. Key = dist_bits<<32 | (8191-orig)<<13 | slot: max == (largest dist,
// then smallest ORIGINAL index) == jnp.argmax first-occurrence semantics.
// The d() arithmetic is bit-identical to rounds 1-4 (contract off,
// ((dx2+dy2)+dz2)); skipped updates are exact no-ops, so selection is exact.
// ---------------------------------------------------------------------------
__global__ __launch_bounds__(FPS_T) void fps_kernel(
    const float* __restrict__ points, float* __restrict__ new_xyz)
{
#pragma clang fp contract(off)
    const int b    = blockIdx.x;
    const int t    = threadIdx.x;
    const int lane = t & 63;
    const int w    = t >> 6;
    const float* pts = points + (size_t)b * NPTS * 3;

    __shared__ float4 pxyzd[NPTS];                 // 131072 B
    __shared__ unsigned short orig16[NPTS];        //  16384 B
    __shared__ unsigned long long key_g[FPS_T];    //   2048 B
    __shared__ int start[FPS_T + 1];               //   1028 B
    __shared__ int cursor[FPS_T];                  //   1024 B
    __shared__ unsigned list[FPS_T];               //   1024 B
    __shared__ unsigned long long pk[2][NWAVE];    //     64 B
    __shared__ int cnt2[2];                        //      8 B
    __shared__ float bbr[6][NWAVE];                //     96 B

    // ---------------- setup: bbox ----------------
    float mnx = 1e30f, mny = 1e30f, mnz = 1e30f;
    float mxx = -1e30f, mxy = -1e30f, mxz = -1e30f;
    for (int k = 0; k < KPT; ++k) {
        const int i = (k << 8) + t;
        float xx = pts[3 * i], yy = pts[3 * i + 1], zz = pts[3 * i + 2];
        mnx = fminf(mnx, xx); mxx = fmaxf(mxx, xx);
        mny = fminf(mny, yy); mxy = fmaxf(mxy, yy);
        mnz = fminf(mnz, zz); mxz = fmaxf(mxz, zz);
    }
#pragma unroll
    for (int off = 32; off >= 1; off >>= 1) {
        mnx = fminf(mnx, __shfl_down(mnx, off));
        mny = fminf(mny, __shfl_down(mny, off));
        mnz = fminf(mnz, __shfl_down(mnz, off));
        mxx = fmaxf(mxx, __shfl_down(mxx, off));
        mxy = fmaxf(mxy, __shfl_down(mxy, off));
        mxz = fmaxf(mxz, __shfl_down(mxz, off));
    }
    if (lane == 0) {
        bbr[0][w] = mnx; bbr[1][w] = mny; bbr[2][w] = mnz;
        bbr[3][w] = mxx; bbr[4][w] = mxy; bbr[5][w] = mxz;
    }
    cursor[t] = 0;                       // histogram zero
    if (t < 2) cnt2[t] = 0;
    __syncthreads();
    mnx = fminf(fminf(bbr[0][0], bbr[0][1]), fminf(bbr[0][2], bbr[0][3]));
    mny = fminf(fminf(bbr[1][0], bbr[1][1]), fminf(bbr[1][2], bbr[1][3]));
    mnz = fminf(fminf(bbr[2][0], bbr[2][1]), fminf(bbr[2][2], bbr[2][3]));
    mxx = fmaxf(fmaxf(bbr[3][0], bbr[3][1]), fmaxf(bbr[3][2], bbr[3][3]));
    mxy = fmaxf(fmaxf(bbr[4][0], bbr[4][1]), fmaxf(bbr[4][2], bbr[4][3]));
    mxz = fmaxf(fmaxf(bbr[5][0], bbr[5][1]), fmaxf(bbr[5][2], bbr[5][3]));
    const float rx = mxx - mnx, ry = mxy - mny, rz = mxz - mnz;
    const float sclx = (rx > 0.f) ? 8.0f / rx : 0.f;
    const float scly = (ry > 0.f) ? 8.0f / ry : 0.f;
    const float sclz = (rz > 0.f) ? 4.0f / rz : 0.f;

    // ---------------- setup: histogram ----------------
    for (int k = 0; k < KPT; ++k) {
        const int i = (k << 8) + t;
        float xx = pts[3 * i], yy = pts[3 * i + 1], zz = pts[3 * i + 2];
        int cxi = min(7, max(0, (int)((xx - mnx) * sclx)));
        int cyi = min(7, max(0, (int)((yy - mny) * scly)));
        int czi = min(3, max(0, (int)((zz - mnz) * sclz)));
        atomicAdd(&cursor[cxi | (cyi << 3) | (czi << 6)], 1);
    }
    __syncthreads();
    if (t == 0) {
        int acc = 0;
        for (int g = 0; g < FPS_T; ++g) { start[g] = acc; acc += cursor[g]; }
        start[FPS_T] = acc;
    }
    __syncthreads();
    const int s0_reg  = start[t];
    int       len_reg = start[t + 1] - s0_reg;
    if (len_reg > 2047) len_reg = 2047;   // cannot happen for sane inputs
    cursor[t] = s0_reg;                   // scatter cursors
    __syncthreads();

    // ---------------- setup: scatter (counting sort) ----------------
    for (int k = 0; k < KPT; ++k) {
        const int i = (k << 8) + t;
        float xx = pts[3 * i], yy = pts[3 * i + 1], zz = pts[3 * i + 2];
        int cxi = min(7, max(0, (int)((xx - mnx) * sclx)));
        int cyi = min(7, max(0, (int)((yy - mny) * scly)));
        int czi = min(3, max(0, (int)((zz - mnz) * sclz)));
        int slot = atomicAdd(&cursor[cxi | (cyi << 3) | (czi << 6)], 1);
        pxyzd[slot] = make_float4(xx, yy, zz, 10000000000.0f);
        orig16[slot] = (unsigned short)i;
    }

    // thread t's bucket box (analytic cell bounds)
    const float cwx = rx * 0.125f, cwy = ry * 0.125f, cwz = rz * 0.25f;
    const float bxl = mnx + (float)(t & 7) * cwx,        bxh = bxl + cwx;
    const float byl = mny + (float)((t >> 3) & 7) * cwy, byh = byl + cwy;
    const float bzl = mnz + (float)(t >> 6) * cwz,       bzh = bzl + cwz;

    // first center = point 0
    float cx = pts[0], cy = pts[1], cz = pts[2];
    if (t == 0) {
        float* o = new_xyz + (size_t)b * NPOINT * 3;
        o[0] = cx; o[1] = cy; o[2] = cz;
    }
    // cached key of own bucket: dist=1e10 => never skipped at it=1
    unsigned long long kk =
        ((unsigned long long)__float_as_uint(10000000000.0f) << 32);
    __syncthreads();

    // ---------------- main loop ----------------
    for (int it = 1; it < NPOINT; ++it) {
        const int par = it & 1;
        // phase 1: box test + compact scan list
        float ddx = fmaxf(fmaxf(bxl - cx, cx - bxh), 0.0f);
        float ddy = fmaxf(fmaxf(byl - cy, cy - byh), 0.0f);
        float ddz = fmaxf(fmaxf(bzl - cz, cz - bzh), 0.0f);
        float dmin2 = ddx * ddx + ddy * ddy + ddz * ddz;
        float ub = __uint_as_float((unsigned)(kk >> 32));
        bool scan = dmin2 < ub * 1.0001f + 1e-5f;   // margin >> fp32 rounding
        unsigned long long m = __ballot(scan);
        int base;
        if (lane == 0) base = atomicAdd(&cnt2[par], __popcll(m));
        base = __builtin_amdgcn_readfirstlane(base);
        if (scan) {
            int pos = base + __popcll(m & ((1ull << lane) - 1ull));
            list[pos] = (unsigned)((t << 24) | (s0_reg << 11) | len_reg);
        }
        if (t == 0) cnt2[1 - par] = 0;
        __syncthreads();                                    // A: list ready
        const int nb = cnt2[par];

        // phase 2: wave work-queue over flagged buckets
        for (int li = w; li < nb; li += NWAVE) {
            unsigned e = list[li];
            int g  = e >> 24;
            int s0 = (e >> 11) & 0x1FFF;
            int ln = e & 0x7FF;
            unsigned long long bk = 0;
            for (int jo = lane; jo < ln; jo += 64) {
                int j = s0 + jo;
                float4 pd = pxyzd[j];
                float dx = pd.x - cx, dy = pd.y - cy, dz = pd.z - cz;
                float d  = ((dx * dx) + (dy * dy)) + (dz * dz);
                float nd = fminf(pd.w, d);
                pxyzd[j].w = nd;
                unsigned long long kkey =
                    ((unsigned long long)__float_as_uint(nd) << 32)
                  | ((unsigned)(8191 - (int)orig16[j]) << 13) | (unsigned)j;
                if (kkey > bk) bk = kkey;
            }
            DPP_REDUCE_MAX(bk);
            if (lane == 63) key_g[g] = bk;
        }
        __syncthreads();                                    // B: keys fresh

        // phase 3: block argmax over 256 bucket keys
        kk = key_g[t];               // fresh read doubles as next iter's ub
        unsigned long long r = kk;
        DPP_REDUCE_MAX(r);
        if (lane == 63) pk[par][w] = r;
        __syncthreads();                                    // C: partials
        unsigned long long k0 = pk[par][0], k1 = pk[par][1];
        unsigned long long k2 = pk[par][2], k3 = pk[par][3];
        if (k1 > k0) k0 = k1;
        if (k3 > k2) k2 = k3;
        if (k2 > k0) k0 = k2;
        const int slot = (int)(k0 & 0x1FFF);
        float4 wc = pxyzd[slot];
        cx = wc.x; cy = wc.y; cz = wc.z;
        if (t == 0) {
            float* o = new_xyz + ((size_t)b * NPOINT + it) * 3;
            o[0] = cx; o[1] = cy; o[2] = cz;
        }
    }
}

// ---------------------------------------------------------------------------
// Ball query: one wave per center. Ascending scan collects the first (i.e.
// smallest-index) NSAMPLE points with d2 < r2, padded with the first hit.
// ---------------------------------------------------------------------------
__global__ __launch_bounds__(256) void ballq_kernel(
    const float* __restrict__ points, const float* __restrict__ new_xyz,
    int* __restrict__ ballidx)
{
#pragma clang fp contract(off)
    const int wid  = (int)((blockIdx.x * 256 + threadIdx.x) >> 6);
    const int lane = threadIdx.x & 63;
    const int b = wid / NPOINT;
    const float* ctr = new_xyz + (size_t)wid * 3;
    const float cx = ctr[0], cy = ctr[1], cz = ctr[2];
    const float* pts = points + (size_t)b * NPTS * 3;
    int* out = ballidx + (size_t)wid * NSAMPLE;
    // NumPy/JAX promote the python double 0.04 to f32 — NOT 0.2f*0.2f.
    const float r2 = (float)(0.2 * 0.2);

    int cnt = 0;
    int first = 0;
    bool havefirst = false;
    for (int base = 0; base < NPTS && cnt < NSAMPLE; base += 64) {
        const int j = base + lane;
        float dx = pts[3 * j + 0] - cx;
        float dy = pts[3 * j + 1] - cy;
        float dz = pts[3 * j + 2] - cz;
        float d2 = ((dx * dx) + (dy * dy)) + (dz * dz);
        const bool in = d2 < r2;
        unsigned long long m = __ballot(in);
        if (in) {
            int pos = cnt + __popcll(m & ((1ull << lane) - 1ull));
            if (pos < NSAMPLE) out[pos] = j;
        }
        if (!havefirst && m != 0ull) {
            first = base + (__ffsll((long long)m) - 1);
            havefirst = true;
        }
        cnt += __popcll(m);
    }
    if (lane >= cnt && lane < NSAMPLE) out[lane] = first;  // pad with first
}

// ---------------------------------------------------------------------------
// Gather + conv: block = NP centers, 128 threads = 128 output channels.
// g[p][c][s] staged in LDS; fp32 FMA accumulate (tolerance is loose here).
// ---------------------------------------------------------------------------
__global__ __launch_bounds__(128) void conv_kernel(
    const float* __restrict__ points, const float* __restrict__ features,
    const float* __restrict__ weight, const float* __restrict__ new_xyz,
    const int* __restrict__ ballidx, float* __restrict__ conv_out)
{
    __shared__ float g[NP][NCH][NSAMPLE];
    const int t = threadIdx.x;
    const int bp0 = blockIdx.x * NP;                // global center index base
    const int b = bp0 / NPOINT;
    const float* pts = points + (size_t)b * NPTS * 3;
    const float* fts = features + (size_t)b * NPTS * 64;

    // gather: 128 slots == 128 threads; slot = p*32+s
    {
        const int p = t >> 5;
        const int s = t & 31;
        const int ci = bp0 + p;
        const int j = ballidx[(size_t)ci * NSAMPLE + s];
        const float* ctr = new_xyz + (size_t)ci * 3;
        const float* pj = pts + 3 * j;
        g[p][0][s] = pj[0] - ctr[0];
        g[p][1][s] = pj[1] - ctr[1];
        g[p][2][s] = pj[2] - ctr[2];
        const float4* fj = (const float4*)(fts + (size_t)j * 64);
#pragma unroll
        for (int c4 = 0; c4 < 16; ++c4) {
            float4 v = fj[c4];
            g[p][3 + 4 * c4 + 0][s] = v.x;
            g[p][3 + 4 * c4 + 1][s] = v.y;
            g[p][3 + 4 * c4 + 2][s] = v.z;
            g[p][3 + 4 * c4 + 3][s] = v.w;
        }
    }
    __syncthreads();

    const int o = t;
    float acc0 = 0.f, acc1 = 0.f, acc2 = 0.f, acc3 = 0.f;
    const float* wr = weight + (size_t)o * NCH * NSAMPLE;
    for (int c = 0; c < NCH; ++c) {
        const float4* w4 = (const float4*)(wr + c * NSAMPLE);
#pragma unroll
        for (int s4 = 0; s4 < 8; ++s4) {
            float4 wv = w4[s4];
            float4 g0 = *(const float4*)&g[0][c][s4 * 4];
            float4 g1 = *(const float4*)&g[1][c][s4 * 4];
            float4 g2 = *(const float4*)&g[2][c][s4 * 4];
            float4 g3 = *(const float4*)&g[3][c][s4 * 4];
            acc0 += g0.x * wv.x + g0.y * wv.y + g0.z * wv.z + g0.w * wv.w;
            acc1 += g1.x * wv.x + g1.y * wv.y + g1.z * wv.z + g1.w * wv.w;
            acc2 += g2.x * wv.x + g2.y * wv.y + g2.z * wv.z + g2.w * wv.w;
            acc3 += g3.x * wv.x + g3.y * wv.y + g3.z * wv.z + g3.w * wv.w;
        }
    }
    float* outp = conv_out + (size_t)bp0 * NOUT;
    outp[0 * NOUT + o] = acc0;
    outp[1 * NOUT + o] = acc1;
    outp[2 * NOUT + o] = acc2;
    outp[3 * NOUT + o] = acc3;
}

extern "C" void kernel_launch(void* const* d_in, const int* in_sizes, int n_in,
                              void* d_out, int out_size, void* d_ws, size_t ws_size,
                              hipStream_t stream)
{
    const float* points   = (const float*)d_in[0];
    const float* features = (const float*)d_in[1];
    const float* weight   = (const float*)d_in[2];

    float* new_xyz = (float*)d_out;                              // (4,2048,3)
    float* conv    = (float*)d_out + (size_t)BATCH * NPOINT * 3; // (4,2048,128)

    int* ballidx = (int*)d_ws;                 // (4,2048,32)

    fps_kernel<<<BATCH, FPS_T, 0, stream>>>(points, new_xyz);
    ballq_kernel<<<(BATCH * NPOINT * 64) / 256, 256, 0, stream>>>(points, new_xyz, ballidx);
    conv_kernel<<<(BATCH * NPOINT) / NP, 128, 0, stream>>>(points, features, weight, new_xyz, ballidx, conv);
}

// Round 6
// 2386.884 us; speedup vs baseline: 1.1955x; 1.1955x over previous
//
#include <hip/hip_runtime.h>

#define BATCH   4
#define NPTS    8192
#define NPOINT  2048
#define NSAMPLE 32
#define NCH     67
#define NOUT    128
#define NP      4      // centers per conv block
#define FPS_T   512
#define NWAVE   (FPS_T / 64)     // 8 waves (2 per SIMD)
#define KPT     (NPTS / FPS_T)   // 16 points per thread (setup passes)
#define NBKT    64               // 4x4x4 spatial buckets, bucket == lane

// DPP ctrl encodings (gfx9/CDNA)
#define DPP_ROW_SHR1    0x111
#define DPP_ROW_SHR2    0x112
#define DPP_ROW_SHR4    0x114
#define DPP_ROW_SHR8    0x118
#define DPP_ROW_BCAST15 0x142
#define DPP_ROW_BCAST31 0x143

// max-combine one DPP hop on a packed u64 key. bound_ctrl=1 zero-fills edge
// lanes; 0 is a safe identity (real keys always have nonzero payload bits).
#define DPP_MAX_HOP(key, ctrl)                                                 \
    {                                                                          \
        int _lo = (int)(unsigned)(key);                                        \
        int _hi = (int)(unsigned)((key) >> 32);                                \
        int _olo = __builtin_amdgcn_update_dpp(0, _lo, (ctrl), 0xF, 0xF, true);\
        int _ohi = __builtin_amdgcn_update_dpp(0, _hi, (ctrl), 0xF, 0xF, true);\
        unsigned long long _o =                                                \
            ((unsigned long long)(unsigned)_ohi << 32) | (unsigned)_olo;       \
        if (_o > (key)) (key) = _o;                                            \
    }

#define DPP_REDUCE_MAX(key)            \
    DPP_MAX_HOP(key, DPP_ROW_SHR1);    \
    DPP_MAX_HOP(key, DPP_ROW_SHR2);    \
    DPP_MAX_HOP(key, DPP_ROW_SHR4);    \
    DPP_MAX_HOP(key, DPP_ROW_SHR8);    \
    DPP_MAX_HOP(key, DPP_ROW_BCAST15); \
    DPP_MAX_HOP(key, DPP_ROW_BCAST31);

// ---------------------------------------------------------------------------
// Bucketed FPS v2. One block/batch, 512 threads (8 waves, 2/SIMD for latency
// overlap). Points counting-sorted into 64 spatial buckets (4x4x4); bucket g
// owned by lane g of EVERY wave (all waves compute the identical flagged
// mask via ballot, so no list/atomics/extra barrier). LDS is SoA stride-1
// float arrays -> conflict-free b32 access. Per iter: box-skip test ->
// ballot -> waves scan flagged buckets (rank mod 8) updating dists + bucket
// max-key -> ONE barrier -> masked refresh of cached keys -> DPP argmax ->
// readlane broadcast of winner slot -> coords from LDS.
// Exactness: d formula identical to R1-5 (contract off, ((dx2+dy2)+dz2));
// a skipped bucket satisfies dmin2(center,box) >= ub >= every dist inside,
// so its updates are provable no-ops and its cached key stays valid. Key =
// dist_bits<<32 | (8191-orig)<<13 | slot gives first-occurrence argmax.
// ---------------------------------------------------------------------------
__global__ __launch_bounds__(FPS_T) void fps_kernel(
    const float* __restrict__ points, float* __restrict__ new_xyz)
{
#pragma clang fp contract(off)
    const int b    = blockIdx.x;
    const int t    = threadIdx.x;
    const int lane = t & 63;
    const int w    = t >> 6;
    const float* pts = points + (size_t)b * NPTS * 3;

    __shared__ float lx[NPTS], ly[NPTS], lz[NPTS], pd[NPTS];  // 131072 B
    __shared__ unsigned short orig16[NPTS];                   //  16384 B
    __shared__ unsigned long long key_g[2][NBKT];             //   1024 B
    __shared__ int start[NBKT + 1];                           //    260 B
    __shared__ int cursor[NBKT];                              //    256 B
    __shared__ float bbr[6][NWAVE];                           //    192 B

    // ---------------- setup: bbox ----------------
    float mnx = 1e30f, mny = 1e30f, mnz = 1e30f;
    float mxx = -1e30f, mxy = -1e30f, mxz = -1e30f;
    for (int k = 0; k < KPT; ++k) {
        const int i = k * FPS_T + t;
        float xx = pts[3 * i], yy = pts[3 * i + 1], zz = pts[3 * i + 2];
        mnx = fminf(mnx, xx); mxx = fmaxf(mxx, xx);
        mny = fminf(mny, yy); mxy = fmaxf(mxy, yy);
        mnz = fminf(mnz, zz); mxz = fmaxf(mxz, zz);
    }
#pragma unroll
    for (int off = 32; off >= 1; off >>= 1) {
        mnx = fminf(mnx, __shfl_down(mnx, off));
        mny = fminf(mny, __shfl_down(mny, off));
        mnz = fminf(mnz, __shfl_down(mnz, off));
        mxx = fmaxf(mxx, __shfl_down(mxx, off));
        mxy = fmaxf(mxy, __shfl_down(mxy, off));
        mxz = fmaxf(mxz, __shfl_down(mxz, off));
    }
    if (lane == 0) {
        bbr[0][w] = mnx; bbr[1][w] = mny; bbr[2][w] = mnz;
        bbr[3][w] = mxx; bbr[4][w] = mxy; bbr[5][w] = mxz;
    }
    if (t < NBKT) cursor[t] = 0;
    __syncthreads();
    mnx = bbr[0][0]; mny = bbr[1][0]; mnz = bbr[2][0];
    mxx = bbr[3][0]; mxy = bbr[4][0]; mxz = bbr[5][0];
#pragma unroll
    for (int q = 1; q < NWAVE; ++q) {
        mnx = fminf(mnx, bbr[0][q]); mny = fminf(mny, bbr[1][q]);
        mnz = fminf(mnz, bbr[2][q]); mxx = fmaxf(mxx, bbr[3][q]);
        mxy = fmaxf(mxy, bbr[4][q]); mxz = fmaxf(mxz, bbr[5][q]);
    }
    const float rx = mxx - mnx, ry = mxy - mny, rz = mxz - mnz;
    const float sclx = (rx > 0.f) ? 4.0f / rx : 0.f;
    const float scly = (ry > 0.f) ? 4.0f / ry : 0.f;
    const float sclz = (rz > 0.f) ? 4.0f / rz : 0.f;

    // ---------------- setup: histogram ----------------
    for (int k = 0; k < KPT; ++k) {
        const int i = k * FPS_T + t;
        float xx = pts[3 * i], yy = pts[3 * i + 1], zz = pts[3 * i + 2];
        int cxi = min(3, max(0, (int)((xx - mnx) * sclx)));
        int cyi = min(3, max(0, (int)((yy - mny) * scly)));
        int czi = min(3, max(0, (int)((zz - mnz) * sclz)));
        atomicAdd(&cursor[cxi | (cyi << 2) | (czi << 4)], 1);
    }
    __syncthreads();
    if (t == 0) {
        int acc = 0;
        for (int g = 0; g < NBKT; ++g) { start[g] = acc; acc += cursor[g]; }
        start[NBKT] = acc;
    }
    __syncthreads();
    const int vs0 = start[lane];                 // per-lane bucket start
    const int vln = start[lane + 1] - vs0;       // per-lane bucket length
    if (t < NBKT) cursor[t] = start[t];          // scatter cursors
    __syncthreads();

    // ---------------- setup: scatter (counting sort) ----------------
    for (int k = 0; k < KPT; ++k) {
        const int i = k * FPS_T + t;
        float xx = pts[3 * i], yy = pts[3 * i + 1], zz = pts[3 * i + 2];
        int cxi = min(3, max(0, (int)((xx - mnx) * sclx)));
        int cyi = min(3, max(0, (int)((yy - mny) * scly)));
        int czi = min(3, max(0, (int)((zz - mnz) * sclz)));
        int slot = atomicAdd(&cursor[cxi | (cyi << 2) | (czi << 4)], 1);
        lx[slot] = xx; ly[slot] = yy; lz[slot] = zz;
        pd[slot] = 10000000000.0f;
        orig16[slot] = (unsigned short)i;
    }

    // lane's bucket box (analytic cell bounds)
    const float cwx = rx * 0.25f, cwy = ry * 0.25f, cwz = rz * 0.25f;
    const float bxl = mnx + (float)(lane & 3) * cwx,        bxh = bxl + cwx;
    const float byl = mny + (float)((lane >> 2) & 3) * cwy, byh = byl + cwy;
    const float bzl = mnz + (float)((lane >> 4) & 3) * cwz, bzh = bzl + cwz;

    // first center = point 0
    float cx = pts[0], cy = pts[1], cz = pts[2];
    if (t == 0) {
        float* o = new_xyz + (size_t)b * NPOINT * 3;
        o[0] = cx; o[1] = cy; o[2] = cz;
    }
    // cached key of lane's bucket: dist=1e10 => flagged at it=1
    unsigned long long kk =
        ((unsigned long long)__float_as_uint(10000000000.0f) << 32);
    __syncthreads();

    // ---------------- main loop ----------------
    for (int it = 1; it < NPOINT; ++it) {
        const int par = it & 1;

        // phase 1: box-skip test; ballot mask identical in all 8 waves
        float ddx = fmaxf(fmaxf(bxl - cx, cx - bxh), 0.0f);
        float ddy = fmaxf(fmaxf(byl - cy, cy - byh), 0.0f);
        float ddz = fmaxf(fmaxf(bzl - cz, cz - bzh), 0.0f);
        float dmin2 = ddx * ddx + ddy * ddy + ddz * ddz;
        float ub = __uint_as_float((unsigned)(kk >> 32));
        bool scan = dmin2 < ub * 1.0001f + 1e-5f;   // margin >> fp32 rounding
        unsigned long long m = __ballot(scan);

        // phase 2: waves scan flagged buckets, rank mod NWAVE partition
        {
            unsigned long long mm = m;
            int r = 0;
            while (mm) {
                const int g = __ffsll((long long)mm) - 1;
                mm &= mm - 1;
                if ((r & (NWAVE - 1)) == w) {
                    const int s0 = __builtin_amdgcn_readlane(vs0, g);
                    const int ln = __builtin_amdgcn_readlane(vln, g);
                    unsigned long long bk = 0;
                    for (int jo = lane; jo < ln; jo += 64) {
                        const int j = s0 + jo;
                        float dx = lx[j] - cx;
                        float dy = ly[j] - cy;
                        float dz = lz[j] - cz;
                        float d  = ((dx * dx) + (dy * dy)) + (dz * dz);
                        float nd = fminf(pd[j], d);
                        pd[j] = nd;
                        unsigned long long kkey =
                            ((unsigned long long)__float_as_uint(nd) << 32)
                          | ((unsigned)(8191 - (int)orig16[j]) << 13)
                          | (unsigned)j;
                        if (kkey > bk) bk = kkey;
                    }
                    DPP_REDUCE_MAX(bk);
                    if (lane == 63) key_g[par][g] = bk;
                }
                ++r;
            }
        }
        __syncthreads();   // the ONE barrier: all key_g/pd writes visible

        // phase 3: refresh cached keys for scanned buckets, DPP argmax
        if ((m >> lane) & 1ull) kk = key_g[par][lane];
        unsigned long long rr = kk;
        DPP_REDUCE_MAX(rr);
        const unsigned rlo =
            (unsigned)__builtin_amdgcn_readlane((int)(unsigned)rr, 63);
        const int slot = (int)(rlo & 0x1FFFu);
        cx = lx[slot]; cy = ly[slot]; cz = lz[slot];   // broadcast reads
        if (t == 0) {
            float* o = new_xyz + ((size_t)b * NPOINT + it) * 3;
            o[0] = cx; o[1] = cy; o[2] = cz;
        }
    }
}

// ---------------------------------------------------------------------------
// Ball query: one wave per center. Ascending scan collects the first (i.e.
// smallest-index) NSAMPLE points with d2 < r2, padded with the first hit.
// ---------------------------------------------------------------------------
__global__ __launch_bounds__(256) void ballq_kernel(
    const float* __restrict__ points, const float* __restrict__ new_xyz,
    int* __restrict__ ballidx)
{
#pragma clang fp contract(off)
    const int wid  = (int)((blockIdx.x * 256 + threadIdx.x) >> 6);
    const int lane = threadIdx.x & 63;
    const int b = wid / NPOINT;
    const float* ctr = new_xyz + (size_t)wid * 3;
    const float cx = ctr[0], cy = ctr[1], cz = ctr[2];
    const float* pts = points + (size_t)b * NPTS * 3;
    int* out = ballidx + (size_t)wid * NSAMPLE;
    // NumPy/JAX promote the python double 0.04 to f32 — NOT 0.2f*0.2f.
    const float r2 = (float)(0.2 * 0.2);

    int cnt = 0;
    int first = 0;
    bool havefirst = false;
    for (int base = 0; base < NPTS && cnt < NSAMPLE; base += 64) {
        const int j = base + lane;
        float dx = pts[3 * j + 0] - cx;
        float dy = pts[3 * j + 1] - cy;
        float dz = pts[3 * j + 2] - cz;
        float d2 = ((dx * dx) + (dy * dy)) + (dz * dz);
        const bool in = d2 < r2;
        unsigned long long m = __ballot(in);
        if (in) {
            int pos = cnt + __popcll(m & ((1ull << lane) - 1ull));
            if (pos < NSAMPLE) out[pos] = j;
        }
        if (!havefirst && m != 0ull) {
            first = base + (__ffsll((long long)m) - 1);
            havefirst = true;
        }
        cnt += __popcll(m);
    }
    if (lane >= cnt && lane < NSAMPLE) out[lane] = first;  // pad with first
}

// ---------------------------------------------------------------------------
// Gather + conv: block = NP centers, 128 threads = 128 output channels.
// g[p][c][s] staged in LDS; fp32 FMA accumulate (tolerance is loose here).
// ---------------------------------------------------------------------------
__global__ __launch_bounds__(128) void conv_kernel(
    const float* __restrict__ points, const float* __restrict__ features,
    const float* __restrict__ weight, const float* __restrict__ new_xyz,
    const int* __restrict__ ballidx, float* __restrict__ conv_out)
{
    __shared__ float g[NP][NCH][NSAMPLE];
    const int t = threadIdx.x;
    const int bp0 = blockIdx.x * NP;                // global center index base
    const int b = bp0 / NPOINT;
    const float* pts = points + (size_t)b * NPTS * 3;
    const float* fts = features + (size_t)b * NPTS * 64;

    // gather: 128 slots == 128 threads; slot = p*32+s
    {
        const int p = t >> 5;
        const int s = t & 31;
        const int ci = bp0 + p;
        const int j = ballidx[(size_t)ci * NSAMPLE + s];
        const float* ctr = new_xyz + (size_t)ci * 3;
        const float* pj = pts + 3 * j;
        g[p][0][s] = pj[0] - ctr[0];
        g[p][1][s] = pj[1] - ctr[1];
        g[p][2][s] = pj[2] - ctr[2];
        const float4* fj = (const float4*)(fts + (size_t)j * 64);
#pragma unroll
        for (int c4 = 0; c4 < 16; ++c4) {
            float4 v = fj[c4];
            g[p][3 + 4 * c4 + 0][s] = v.x;
            g[p][3 + 4 * c4 + 1][s] = v.y;
            g[p][3 + 4 * c4 + 2][s] = v.z;
            g[p][3 + 4 * c4 + 3][s] = v.w;
        }
    }
    __syncthreads();

    const int o = t;
    float acc0 = 0.f, acc1 = 0.f, acc2 = 0.f, acc3 = 0.f;
    const float* wr = weight + (size_t)o * NCH * NSAMPLE;
    for (int c = 0; c < NCH; ++c) {
        const float4* w4 = (const float4*)(wr + c * NSAMPLE);
#pragma unroll
        for (int s4 = 0; s4 < 8; ++s4) {
            float4 wv = w4[s4];
            float4 g0 = *(const float4*)&g[0][c][s4 * 4];
            float4 g1 = *(const float4*)&g[1][c][s4 * 4];
            float4 g2 = *(const float4*)&g[2][c][s4 * 4];
            float4 g3 = *(const float4*)&g[3][c][s4 * 4];
            acc0 += g0.x * wv.x + g0.y * wv.y + g0.z * wv.z + g0.w * wv.w;
            acc1 += g1.x * wv.x + g1.y * wv.y + g1.z * wv.z + g1.w * wv.w;
            acc2 += g2.x * wv.x + g2.y * wv.y + g2.z * wv.z + g2.w * wv.w;
            acc3 += g3.x * wv.x + g3.y * wv.y + g3.z * wv.z + g3.w * wv.w;
        }
    }
    float* outp = conv_out + (size_t)bp0 * NOUT;
    outp[0 * NOUT + o] = acc0;
    outp[1 * NOUT + o] = acc1;
    outp[2 * NOUT + o] = acc2;
    outp[3 * NOUT + o] = acc3;
}

extern "C" void kernel_launch(void* const* d_in, const int* in_sizes, int n_in,
                              void* d_out, int out_size, void* d_ws, size_t ws_size,
                              hipStream_t stream)
{
    const float* points   = (const float*)d_in[0];
    const float* features = (const float*)d_in[1];
    const float* weight   = (const float*)d_in[2];

    float* new_xyz = (float*)d_out;                              // (4,2048,3)
    float* conv    = (float*)d_out + (size_t)BATCH * NPOINT * 3; // (4,2048,128)

    int* ballidx = (int*)d_ws;                 // (4,2048,32)

    fps_kernel<<<BATCH, FPS_T, 0, stream>>>(points, new_xyz);
    ballq_kernel<<<(BATCH * NPOINT * 64) / 256, 256, 0, stream>>>(points, new_xyz, ballidx);
    conv_kernel<<<(BATCH * NPOINT) / NP, 128, 0, stream>>>(points, features, weight, new_xyz, ballidx, conv);
}

// Round 7
// 2018.456 us; speedup vs baseline: 1.4137x; 1.1825x over previous
//
#include <hip/hip_runtime.h>

#define BATCH   4
#define NPTS    8192
#define NPOINT  2048
#define NSAMPLE 32
#define NCH     67
#define NOUT    128
#define NP      4      // centers per conv block
#define FPS_T   512
#define NWAVE   (FPS_T / 64)     // 8 waves (2 per SIMD)
#define KPT     (NPTS / FPS_T)   // 16 points per thread (setup passes)
#define NBKT    64               // 4x4x4 spatial buckets, bucket == lane

// DPP ctrl encodings (gfx9/CDNA)
#define DPP_ROW_SHR1    0x111
#define DPP_ROW_SHR2    0x112
#define DPP_ROW_SHR4    0x114
#define DPP_ROW_SHR8    0x118
#define DPP_ROW_BCAST15 0x142
#define DPP_ROW_BCAST31 0x143

// max-combine one DPP hop on a packed u64 key. bound_ctrl=1 zero-fills edge
// lanes; 0 is a safe identity (real keys always have nonzero payload bits).
#define DPP_MAX_HOP(key, ctrl)                                                 \
    {                                                                          \
        int _lo = (int)(unsigned)(key);                                        \
        int _hi = (int)(unsigned)((key) >> 32);                                \
        int _olo = __builtin_amdgcn_update_dpp(0, _lo, (ctrl), 0xF, 0xF, true);\
        int _ohi = __builtin_amdgcn_update_dpp(0, _hi, (ctrl), 0xF, 0xF, true);\
        unsigned long long _o =                                                \
            ((unsigned long long)(unsigned)_ohi << 32) | (unsigned)_olo;       \
        if (_o > (key)) (key) = _o;                                            \
    }

#define DPP_REDUCE_MAX(key)            \
    DPP_MAX_HOP(key, DPP_ROW_SHR1);    \
    DPP_MAX_HOP(key, DPP_ROW_SHR2);    \
    DPP_MAX_HOP(key, DPP_ROW_SHR4);    \
    DPP_MAX_HOP(key, DPP_ROW_SHR8);    \
    DPP_MAX_HOP(key, DPP_ROW_BCAST15); \
    DPP_MAX_HOP(key, DPP_ROW_BCAST31);

// ---------------------------------------------------------------------------
// Bucketed FPS v3. One block/batch, 512 threads (8 waves, 2/SIMD). Points
// counting-sorted into 64 spatial buckets (4x4x4); bucket g owned by lane g.
// Per iter: box-skip test -> ballot m (identical in all waves) -> per-lane
// rank = popc(m below lane); bucket g assigned to wave rank%8; second ballot
// gives each wave its own tiny submask (no global mask walk -> the R6 scalar
// walk was ~20 serial ffs iterations in EVERY wave). LDS is float2 SoA
// (xy, zd) -> 3 DS reads/point, d written to zd[j].y (stride-8, free 2-way
// alias). ONE barrier/iter; cached keys parity-double-buffered.
// Exactness: d formula identical to R1-6 (contract off, ((dx2+dy2)+dz2));
// skipped buckets satisfy dmin2 >= ub >= every dist inside -> updates are
// provable no-ops, cached argmax keys stay valid. Key = dist_bits<<32 |
// (8191-orig)<<13 | slot == first-occurrence argmax by original index.
// ---------------------------------------------------------------------------
__global__ __launch_bounds__(FPS_T) void fps_kernel(
    const float* __restrict__ points, float* __restrict__ new_xyz)
{
#pragma clang fp contract(off)
    const int b    = blockIdx.x;
    const int t    = threadIdx.x;
    const int lane = t & 63;
    const int w    = t >> 6;
    const float* pts = points + (size_t)b * NPTS * 3;

    __shared__ float2 xy[NPTS];                    //  65536 B
    __shared__ float2 zd[NPTS];                    //  65536 B
    __shared__ unsigned short orig16[NPTS];        //  16384 B
    __shared__ unsigned long long key_g[2][NBKT];  //   1024 B
    __shared__ int start[NBKT + 1];                //    260 B
    __shared__ int cursor[NBKT];                   //    256 B
    __shared__ float bbr[6][NWAVE];                //    192 B

    // ---------------- setup: bbox ----------------
    float mnx = 1e30f, mny = 1e30f, mnz = 1e30f;
    float mxx = -1e30f, mxy = -1e30f, mxz = -1e30f;
    for (int k = 0; k < KPT; ++k) {
        const int i = k * FPS_T + t;
        float xx = pts[3 * i], yy = pts[3 * i + 1], zz = pts[3 * i + 2];
        mnx = fminf(mnx, xx); mxx = fmaxf(mxx, xx);
        mny = fminf(mny, yy); mxy = fmaxf(mxy, yy);
        mnz = fminf(mnz, zz); mxz = fmaxf(mxz, zz);
    }
#pragma unroll
    for (int off = 32; off >= 1; off >>= 1) {
        mnx = fminf(mnx, __shfl_down(mnx, off));
        mny = fminf(mny, __shfl_down(mny, off));
        mnz = fminf(mnz, __shfl_down(mnz, off));
        mxx = fmaxf(mxx, __shfl_down(mxx, off));
        mxy = fmaxf(mxy, __shfl_down(mxy, off));
        mxz = fmaxf(mxz, __shfl_down(mxz, off));
    }
    if (lane == 0) {
        bbr[0][w] = mnx; bbr[1][w] = mny; bbr[2][w] = mnz;
        bbr[3][w] = mxx; bbr[4][w] = mxy; bbr[5][w] = mxz;
    }
    if (t < NBKT) cursor[t] = 0;
    __syncthreads();
    mnx = bbr[0][0]; mny = bbr[1][0]; mnz = bbr[2][0];
    mxx = bbr[3][0]; mxy = bbr[4][0]; mxz = bbr[5][0];
#pragma unroll
    for (int q = 1; q < NWAVE; ++q) {
        mnx = fminf(mnx, bbr[0][q]); mny = fminf(mny, bbr[1][q]);
        mnz = fminf(mnz, bbr[2][q]); mxx = fmaxf(mxx, bbr[3][q]);
        mxy = fmaxf(mxy, bbr[4][q]); mxz = fmaxf(mxz, bbr[5][q]);
    }
    const float rx = mxx - mnx, ry = mxy - mny, rz = mxz - mnz;
    const float sclx = (rx > 0.f) ? 4.0f / rx : 0.f;
    const float scly = (ry > 0.f) ? 4.0f / ry : 0.f;
    const float sclz = (rz > 0.f) ? 4.0f / rz : 0.f;

    // ---------------- setup: histogram ----------------
    for (int k = 0; k < KPT; ++k) {
        const int i = k * FPS_T + t;
        float xx = pts[3 * i], yy = pts[3 * i + 1], zz = pts[3 * i + 2];
        int cxi = min(3, max(0, (int)((xx - mnx) * sclx)));
        int cyi = min(3, max(0, (int)((yy - mny) * scly)));
        int czi = min(3, max(0, (int)((zz - mnz) * sclz)));
        atomicAdd(&cursor[cxi | (cyi << 2) | (czi << 4)], 1);
    }
    __syncthreads();
    if (t == 0) {
        int acc = 0;
        for (int g = 0; g < NBKT; ++g) { start[g] = acc; acc += cursor[g]; }
        start[NBKT] = acc;
    }
    __syncthreads();
    const int vs0 = start[lane];                 // per-lane bucket start
    const int vln = start[lane + 1] - vs0;       // per-lane bucket length
    if (t < NBKT) cursor[t] = start[t];          // scatter cursors
    __syncthreads();

    // ---------------- setup: scatter (counting sort) ----------------
    for (int k = 0; k < KPT; ++k) {
        const int i = k * FPS_T + t;
        float xx = pts[3 * i], yy = pts[3 * i + 1], zz = pts[3 * i + 2];
        int cxi = min(3, max(0, (int)((xx - mnx) * sclx)));
        int cyi = min(3, max(0, (int)((yy - mny) * scly)));
        int czi = min(3, max(0, (int)((zz - mnz) * sclz)));
        int slot = atomicAdd(&cursor[cxi | (cyi << 2) | (czi << 4)], 1);
        xy[slot] = make_float2(xx, yy);
        zd[slot] = make_float2(zz, 10000000000.0f);
        orig16[slot] = (unsigned short)i;
    }

    // lane's bucket box (analytic cell bounds)
    const float cwx = rx * 0.25f, cwy = ry * 0.25f, cwz = rz * 0.25f;
    const float bxl = mnx + (float)(lane & 3) * cwx,        bxh = bxl + cwx;
    const float byl = mny + (float)((lane >> 2) & 3) * cwy, byh = byl + cwy;
    const float bzl = mnz + (float)((lane >> 4) & 3) * cwz, bzh = bzl + cwz;
    const unsigned long long below = (1ull << lane) - 1ull;

    // first center = point 0
    float cx = pts[0], cy = pts[1], cz = pts[2];
    if (t == 0) {
        float* o = new_xyz + (size_t)b * NPOINT * 3;
        o[0] = cx; o[1] = cy; o[2] = cz;
    }
    // cached key of lane's bucket: dist=1e10 => flagged at it=1
    unsigned long long kk =
        ((unsigned long long)__float_as_uint(10000000000.0f) << 32);
    __syncthreads();

    // ---------------- main loop ----------------
    for (int it = 1; it < NPOINT; ++it) {
        const int par = it & 1;

        // phase 1: box-skip test; ballot identical in all 8 waves
        float ddx = fmaxf(fmaxf(bxl - cx, cx - bxh), 0.0f);
        float ddy = fmaxf(fmaxf(byl - cy, cy - byh), 0.0f);
        float ddz = fmaxf(fmaxf(bzl - cz, cz - bzh), 0.0f);
        float dmin2 = ddx * ddx + ddy * ddy + ddz * ddz;
        float ub = __uint_as_float((unsigned)(kk >> 32));
        bool scan = dmin2 < ub * 1.0001f + 1e-5f;   // margin >> fp32 rounding
        unsigned long long m = __ballot(scan);

        // rank-based assignment: bucket g -> wave (rank(g) % NWAVE); each
        // wave gets its own tiny submask (typically 1-3 bits), no global walk
        const int rank = (int)__popcll(m & below);
        const bool mine = scan && ((rank & (NWAVE - 1)) == w);
        unsigned long long mw = __ballot(mine);

        // phase 2: this wave scans only its own buckets
        while (mw) {
            const int g = __ffsll((long long)mw) - 1;
            mw &= mw - 1;
            const int s0 = __builtin_amdgcn_readlane(vs0, g);
            const int ln = __builtin_amdgcn_readlane(vln, g);
            unsigned long long bk = 0;
            for (int jo = lane; jo < ln; jo += 64) {
                const int j = s0 + jo;
                float2 vxy = xy[j];
                float2 vzd = zd[j];
                float dx = vxy.x - cx;
                float dy = vxy.y - cy;
                float dz = vzd.x - cz;
                float d  = ((dx * dx) + (dy * dy)) + (dz * dz);
                float nd = fminf(vzd.y, d);
                zd[j].y = nd;
                unsigned long long kkey =
                    ((unsigned long long)__float_as_uint(nd) << 32)
                  | ((unsigned)(8191 - (int)orig16[j]) << 13)
                  | (unsigned)j;
                if (kkey > bk) bk = kkey;
            }
            DPP_REDUCE_MAX(bk);
            if (lane == 63) key_g[par][g] = bk;
        }
        __syncthreads();   // the ONE barrier: all key_g/zd writes visible

        // phase 3: refresh cached keys for scanned buckets, DPP argmax
        if (scan) kk = key_g[par][lane];
        unsigned long long rr = kk;
        DPP_REDUCE_MAX(rr);
        const unsigned rlo =
            (unsigned)__builtin_amdgcn_readlane((int)(unsigned)rr, 63);
        const int slot = (int)(rlo & 0x1FFFu);
        float2 wxy = xy[slot];                      // broadcast reads
        float2 wzd = zd[slot];
        cx = wxy.x; cy = wxy.y; cz = wzd.x;
        if (t == 0) {
            float* o = new_xyz + ((size_t)b * NPOINT + it) * 3;
            o[0] = cx; o[1] = cy; o[2] = cz;
        }
    }
}

// ---------------------------------------------------------------------------
// Ball query: one wave per center. Ascending scan collects the first (i.e.
// smallest-index) NSAMPLE points with d2 < r2, padded with the first hit.
// ---------------------------------------------------------------------------
__global__ __launch_bounds__(256) void ballq_kernel(
    const float* __restrict__ points, const float* __restrict__ new_xyz,
    int* __restrict__ ballidx)
{
#pragma clang fp contract(off)
    const int wid  = (int)((blockIdx.x * 256 + threadIdx.x) >> 6);
    const int lane = threadIdx.x & 63;
    const int b = wid / NPOINT;
    const float* ctr = new_xyz + (size_t)wid * 3;
    const float cx = ctr[0], cy = ctr[1], cz = ctr[2];
    const float* pts = points + (size_t)b * NPTS * 3;
    int* out = ballidx + (size_t)wid * NSAMPLE;
    // NumPy/JAX promote the python double 0.04 to f32 — NOT 0.2f*0.2f.
    const float r2 = (float)(0.2 * 0.2);

    int cnt = 0;
    int first = 0;
    bool havefirst = false;
    for (int base = 0; base < NPTS && cnt < NSAMPLE; base += 64) {
        const int j = base + lane;
        float dx = pts[3 * j + 0] - cx;
        float dy = pts[3 * j + 1] - cy;
        float dz = pts[3 * j + 2] - cz;
        float d2 = ((dx * dx) + (dy * dy)) + (dz * dz);
        const bool in = d2 < r2;
        unsigned long long m = __ballot(in);
        if (in) {
            int pos = cnt + __popcll(m & ((1ull << lane) - 1ull));
            if (pos < NSAMPLE) out[pos] = j;
        }
        if (!havefirst && m != 0ull) {
            first = base + (__ffsll((long long)m) - 1);
            havefirst = true;
        }
        cnt += __popcll(m);
    }
    if (lane >= cnt && lane < NSAMPLE) out[lane] = first;  // pad with first
}

// ---------------------------------------------------------------------------
// Gather + conv: block = NP centers, 128 threads = 128 output channels.
// g[p][c][s] staged in LDS; fp32 FMA accumulate (tolerance is loose here).
// ---------------------------------------------------------------------------
__global__ __launch_bounds__(128) void conv_kernel(
    const float* __restrict__ points, const float* __restrict__ features,
    const float* __restrict__ weight, const float* __restrict__ new_xyz,
    const int* __restrict__ ballidx, float* __restrict__ conv_out)
{
    __shared__ float g[NP][NCH][NSAMPLE];
    const int t = threadIdx.x;
    const int bp0 = blockIdx.x * NP;                // global center index base
    const int b = bp0 / NPOINT;
    const float* pts = points + (size_t)b * NPTS * 3;
    const float* fts = features + (size_t)b * NPTS * 64;

    // gather: 128 slots == 128 threads; slot = p*32+s
    {
        const int p = t >> 5;
        const int s = t & 31;
        const int ci = bp0 + p;
        const int j = ballidx[(size_t)ci * NSAMPLE + s];
        const float* ctr = new_xyz + (size_t)ci * 3;
        const float* pj = pts + 3 * j;
        g[p][0][s] = pj[0] - ctr[0];
        g[p][1][s] = pj[1] - ctr[1];
        g[p][2][s] = pj[2] - ctr[2];
        const float4* fj = (const float4*)(fts + (size_t)j * 64);
#pragma unroll
        for (int c4 = 0; c4 < 16; ++c4) {
            float4 v = fj[c4];
            g[p][3 + 4 * c4 + 0][s] = v.x;
            g[p][3 + 4 * c4 + 1][s] = v.y;
            g[p][3 + 4 * c4 + 2][s] = v.z;
            g[p][3 + 4 * c4 + 3][s] = v.w;
        }
    }
    __syncthreads();

    const int o = t;
    float acc0 = 0.f, acc1 = 0.f, acc2 = 0.f, acc3 = 0.f;
    const float* wr = weight + (size_t)o * NCH * NSAMPLE;
    for (int c = 0; c < NCH; ++c) {
        const float4* w4 = (const float4*)(wr + c * NSAMPLE);
#pragma unroll
        for (int s4 = 0; s4 < 8; ++s4) {
            float4 wv = w4[s4];
            float4 g0 = *(const float4*)&g[0][c][s4 * 4];
            float4 g1 = *(const float4*)&g[1][c][s4 * 4];
            float4 g2 = *(const float4*)&g[2][c][s4 * 4];
            float4 g3 = *(const float4*)&g[3][c][s4 * 4];
            acc0 += g0.x * wv.x + g0.y * wv.y + g0.z * wv.z + g0.w * wv.w;
            acc1 += g1.x * wv.x + g1.y * wv.y + g1.z * wv.z + g1.w * wv.w;
            acc2 += g2.x * wv.x + g2.y * wv.y + g2.z * wv.z + g2.w * wv.w;
            acc3 += g3.x * wv.x + g3.y * wv.y + g3.z * wv.z + g3.w * wv.w;
        }
    }
    float* outp = conv_out + (size_t)bp0 * NOUT;
    outp[0 * NOUT + o] = acc0;
    outp[1 * NOUT + o] = acc1;
    outp[2 * NOUT + o] = acc2;
    outp[3 * NOUT + o] = acc3;
}

extern "C" void kernel_launch(void* const* d_in, const int* in_sizes, int n_in,
                              void* d_out, int out_size, void* d_ws, size_t ws_size,
                              hipStream_t stream)
{
    const float* points   = (const float*)d_in[0];
    const float* features = (const float*)d_in[1];
    const float* weight   = (const float*)d_in[2];

    float* new_xyz = (float*)d_out;                              // (4,2048,3)
    float* conv    = (float*)d_out + (size_t)BATCH * NPOINT * 3; // (4,2048,128)

    int* ballidx = (int*)d_ws;                 // (4,2048,32)

    fps_kernel<<<BATCH, FPS_T, 0, stream>>>(points, new_xyz);
    ballq_kernel<<<(BATCH * NPOINT * 64) / 256, 256, 0, stream>>>(points, new_xyz, ballidx);
    conv_kernel<<<(BATCH * NPOINT) / NP, 128, 0, stream>>>(points, features, weight, new_xyz, ballidx, conv);
}

// Round 8
// 1998.821 us; speedup vs baseline: 1.4276x; 1.0098x over previous
//
#include <hip/hip_runtime.h>

#define BATCH   4
#define NPTS    8192
#define NPOINT  2048
#define NSAMPLE 32
#define NCH     67
#define NOUT    128
#define FPS_T   512
#define NWAVE   (FPS_T / 64)     // 8 waves (2 per SIMD)
#define KPT     (NPTS / FPS_T)   // 16 points per thread (setup passes)
#define NBKT    64               // 4x4x4 spatial buckets, bucket == lane
#define NFPS    4                // fps blocks (one per batch)
#define NBLK    256              // total blocks (all co-resident: <= 256 CUs)
#define TPT     8                // centers per worker ticket
#define NTICK   (BATCH * NPOINT / TPT)   // 1024 tickets

// DPP ctrl encodings (gfx9/CDNA)
#define DPP_ROW_SHR1    0x111
#define DPP_ROW_SHR2    0x112
#define DPP_ROW_SHR4    0x114
#define DPP_ROW_SHR8    0x118
#define DPP_ROW_BCAST15 0x142
#define DPP_ROW_BCAST31 0x143

#define DPP_MAX_HOP(key, ctrl)                                                 \
    {                                                                          \
        int _lo = (int)(unsigned)(key);                                        \
        int _hi = (int)(unsigned)((key) >> 32);                                \
        int _olo = __builtin_amdgcn_update_dpp(0, _lo, (ctrl), 0xF, 0xF, true);\
        int _ohi = __builtin_amdgcn_update_dpp(0, _hi, (ctrl), 0xF, 0xF, true);\
        unsigned long long _o =                                                \
            ((unsigned long long)(unsigned)_ohi << 32) | (unsigned)_olo;       \
        if (_o > (key)) (key) = _o;                                            \
    }

#define DPP_REDUCE_MAX(key)            \
    DPP_MAX_HOP(key, DPP_ROW_SHR1);    \
    DPP_MAX_HOP(key, DPP_ROW_SHR2);    \
    DPP_MAX_HOP(key, DPP_ROW_SHR4);    \
    DPP_MAX_HOP(key, DPP_ROW_SHR8);    \
    DPP_MAX_HOP(key, DPP_ROW_BCAST15); \
    DPP_MAX_HOP(key, DPP_ROW_BCAST31);

// ---------------------------------------------------------------------------
// Fused kernel. Blocks 0-3: bucketed FPS (identical math to R7, bit-exact
// selection) + chunked agent-scope publish of progress. Blocks 4-255:
// workers that grab 8-center tickets, acquire-spin on progress, then do
// per-wave ball query (bit-exact) + gather + conv entirely on-chip.
// Co-residency: 256 blocks of 512 thr, each fits one CU => all resident
// regardless of dispatch order; fps never waits on workers => no deadlock.
// ---------------------------------------------------------------------------
__global__ __launch_bounds__(FPS_T) void fused_kernel(
    const float* __restrict__ points, const float* __restrict__ features,
    const float* __restrict__ weight, float* __restrict__ new_xyz,
    float* __restrict__ conv_out, int* __restrict__ ctl)
{
    __shared__ __attribute__((aligned(16))) char smem[149504];
    const int t    = threadIdx.x;
    const int lane = t & 63;
    const int w    = t >> 6;
    int* prog = ctl;            // prog[0..3], zeroed by hipMemsetAsync
    int* ticket = ctl + 32;     // byte offset 128

    if (blockIdx.x < NFPS) {
        // =================== FPS path (R7 verbatim + publish) ===============
#pragma clang fp contract(off)
        const int b = blockIdx.x;
        const float* pts = points + (size_t)b * NPTS * 3;

        float2* xy = (float2*)smem;                               // 65536
        float2* zd = (float2*)(smem + 65536);                     // 65536
        unsigned short* orig16 = (unsigned short*)(smem + 131072);// 16384
        unsigned long long (*key_g)[NBKT] =
            (unsigned long long (*)[NBKT])(smem + 147456);        // 1024
        int* start  = (int*)(smem + 148480);                      // 260
        int* cursor = (int*)(smem + 148744);                      // 256
        float (*bbr)[NWAVE] = (float (*)[NWAVE])(smem + 149000);  // 192

        // setup: bbox
        float mnx = 1e30f, mny = 1e30f, mnz = 1e30f;
        float mxx = -1e30f, mxy = -1e30f, mxz = -1e30f;
        for (int k = 0; k < KPT; ++k) {
            const int i = k * FPS_T + t;
            float xx = pts[3 * i], yy = pts[3 * i + 1], zz = pts[3 * i + 2];
            mnx = fminf(mnx, xx); mxx = fmaxf(mxx, xx);
            mny = fminf(mny, yy); mxy = fmaxf(mxy, yy);
            mnz = fminf(mnz, zz); mxz = fmaxf(mxz, zz);
        }
#pragma unroll
        for (int off = 32; off >= 1; off >>= 1) {
            mnx = fminf(mnx, __shfl_down(mnx, off));
            mny = fminf(mny, __shfl_down(mny, off));
            mnz = fminf(mnz, __shfl_down(mnz, off));
            mxx = fmaxf(mxx, __shfl_down(mxx, off));
            mxy = fmaxf(mxy, __shfl_down(mxy, off));
            mxz = fmaxf(mxz, __shfl_down(mxz, off));
        }
        if (lane == 0) {
            bbr[0][w] = mnx; bbr[1][w] = mny; bbr[2][w] = mnz;
            bbr[3][w] = mxx; bbr[4][w] = mxy; bbr[5][w] = mxz;
        }
        if (t < NBKT) cursor[t] = 0;
        __syncthreads();
        mnx = bbr[0][0]; mny = bbr[1][0]; mnz = bbr[2][0];
        mxx = bbr[3][0]; mxy = bbr[4][0]; mxz = bbr[5][0];
#pragma unroll
        for (int q = 1; q < NWAVE; ++q) {
            mnx = fminf(mnx, bbr[0][q]); mny = fminf(mny, bbr[1][q]);
            mnz = fminf(mnz, bbr[2][q]); mxx = fmaxf(mxx, bbr[3][q]);
            mxy = fmaxf(mxy, bbr[4][q]); mxz = fmaxf(mxz, bbr[5][q]);
        }
        const float rx = mxx - mnx, ry = mxy - mny, rz = mxz - mnz;
        const float sclx = (rx > 0.f) ? 4.0f / rx : 0.f;
        const float scly = (ry > 0.f) ? 4.0f / ry : 0.f;
        const float sclz = (rz > 0.f) ? 4.0f / rz : 0.f;

        // setup: histogram
        for (int k = 0; k < KPT; ++k) {
            const int i = k * FPS_T + t;
            float xx = pts[3 * i], yy = pts[3 * i + 1], zz = pts[3 * i + 2];
            int cxi = min(3, max(0, (int)((xx - mnx) * sclx)));
            int cyi = min(3, max(0, (int)((yy - mny) * scly)));
            int czi = min(3, max(0, (int)((zz - mnz) * sclz)));
            atomicAdd(&cursor[cxi | (cyi << 2) | (czi << 4)], 1);
        }
        __syncthreads();
        if (t == 0) {
            int acc = 0;
            for (int g = 0; g < NBKT; ++g) { start[g] = acc; acc += cursor[g]; }
            start[NBKT] = acc;
        }
        __syncthreads();
        const int vs0 = start[lane];
        const int vln = start[lane + 1] - vs0;
        if (t < NBKT) cursor[t] = start[t];
        __syncthreads();

        // setup: scatter (counting sort)
        for (int k = 0; k < KPT; ++k) {
            const int i = k * FPS_T + t;
            float xx = pts[3 * i], yy = pts[3 * i + 1], zz = pts[3 * i + 2];
            int cxi = min(3, max(0, (int)((xx - mnx) * sclx)));
            int cyi = min(3, max(0, (int)((yy - mny) * scly)));
            int czi = min(3, max(0, (int)((zz - mnz) * sclz)));
            int slot = atomicAdd(&cursor[cxi | (cyi << 2) | (czi << 4)], 1);
            xy[slot] = make_float2(xx, yy);
            zd[slot] = make_float2(zz, 10000000000.0f);
            orig16[slot] = (unsigned short)i;
        }

        const float cwx = rx * 0.25f, cwy = ry * 0.25f, cwz = rz * 0.25f;
        const float bxl = mnx + (float)(lane & 3) * cwx,        bxh = bxl + cwx;
        const float byl = mny + (float)((lane >> 2) & 3) * cwy, byh = byl + cwy;
        const float bzl = mnz + (float)((lane >> 4) & 3) * cwz, bzh = bzl + cwz;
        const unsigned long long below = (1ull << lane) - 1ull;

        float cx = pts[0], cy = pts[1], cz = pts[2];
        if (t == 0) {
            float* o = new_xyz + (size_t)b * NPOINT * 3;
            o[0] = cx; o[1] = cy; o[2] = cz;
        }
        unsigned long long kk =
            ((unsigned long long)__float_as_uint(10000000000.0f) << 32);
        __syncthreads();

        for (int it = 1; it < NPOINT; ++it) {
            const int par = it & 1;
            float ddx = fmaxf(fmaxf(bxl - cx, cx - bxh), 0.0f);
            float ddy = fmaxf(fmaxf(byl - cy, cy - byh), 0.0f);
            float ddz = fmaxf(fmaxf(bzl - cz, cz - bzh), 0.0f);
            float dmin2 = ddx * ddx + ddy * ddy + ddz * ddz;
            float ub = __uint_as_float((unsigned)(kk >> 32));
            bool scan = dmin2 < ub * 1.0001f + 1e-5f;
            unsigned long long m = __ballot(scan);

            const int rank = (int)__popcll(m & below);
            const bool mine = scan && ((rank & (NWAVE - 1)) == w);
            unsigned long long mw = __ballot(mine);

            while (mw) {
                const int g = __ffsll((long long)mw) - 1;
                mw &= mw - 1;
                const int s0 = __builtin_amdgcn_readlane(vs0, g);
                const int ln = __builtin_amdgcn_readlane(vln, g);
                unsigned long long bk = 0;
                for (int jo = lane; jo < ln; jo += 64) {
                    const int j = s0 + jo;
                    float2 vxy = xy[j];
                    float2 vzd = zd[j];
                    float dx = vxy.x - cx;
                    float dy = vxy.y - cy;
                    float dz = vzd.x - cz;
                    float d  = ((dx * dx) + (dy * dy)) + (dz * dz);
                    float nd = fminf(vzd.y, d);
                    zd[j].y = nd;
                    unsigned long long kkey =
                        ((unsigned long long)__float_as_uint(nd) << 32)
                      | ((unsigned)(8191 - (int)orig16[j]) << 13)
                      | (unsigned)j;
                    if (kkey > bk) bk = kkey;
                }
                DPP_REDUCE_MAX(bk);
                if (lane == 63) key_g[par][g] = bk;
            }
            __syncthreads();

            if (scan) kk = key_g[par][lane];
            unsigned long long rr = kk;
            DPP_REDUCE_MAX(rr);
            const unsigned rlo =
                (unsigned)__builtin_amdgcn_readlane((int)(unsigned)rr, 63);
            const int slot = (int)(rlo & 0x1FFFu);
            float2 wxy = xy[slot];
            float2 wzd = zd[slot];
            cx = wxy.x; cy = wxy.y; cz = wzd.x;
            if (t == 0) {
                float* o = new_xyz + ((size_t)b * NPOINT + it) * 3;
                o[0] = cx; o[1] = cy; o[2] = cz;
                if (((it & 15) == 15) || (it == NPOINT - 1)) {
                    __threadfence();   // drain coord stores, then publish
                    __hip_atomic_store(&prog[b], it + 1, __ATOMIC_RELEASE,
                                       __HIP_MEMORY_SCOPE_AGENT);
                }
            }
        }
        return;
    }

    // ======================= worker path ===================================
    float (*g)[NCH][NSAMPLE] = (float (*)[NCH][NSAMPLE])smem;  // 68608 B
    int (*idx)[NSAMPLE] = (int (*)[NSAMPLE])(smem + 68608);    //  1024 B
    int* tk_s = (int*)(smem + 69632);

    for (;;) {
        if (t == 0) *tk_s = atomicAdd(ticket, 1);
        __syncthreads();
        const int T = *tk_s;
        __syncthreads();
        if (T >= NTICK) break;
        const int b   = T & 3;
        const int it0 = (T >> 2) * TPT;

        // wait until all TPT centers of this ticket are published
        if (t == 0) {
            while (__hip_atomic_load(&prog[b], __ATOMIC_ACQUIRE,
                                     __HIP_MEMORY_SCOPE_AGENT) < it0 + TPT)
                __builtin_amdgcn_s_sleep(8);
        }
        __syncthreads();

        const float* pts = points + (size_t)b * NPTS * 3;
        const float* fts = features + (size_t)b * NPTS * 64;

        // ---- ball query: wave w handles center it0+w (bit-exact R7 logic) --
        {
#pragma clang fp contract(off)
            const int gci = b * NPOINT + it0 + w;
            const float cx = new_xyz[3 * gci + 0];
            const float cy = new_xyz[3 * gci + 1];
            const float cz = new_xyz[3 * gci + 2];
            const float r2 = (float)(0.2 * 0.2);
            int* out = idx[w];
            int cnt = 0, first = 0;
            bool havefirst = false;
            for (int base = 0; base < NPTS && cnt < NSAMPLE; base += 64) {
                const int j = base + lane;
                float dx = pts[3 * j + 0] - cx;
                float dy = pts[3 * j + 1] - cy;
                float dz = pts[3 * j + 2] - cz;
                float d2 = ((dx * dx) + (dy * dy)) + (dz * dz);
                const bool in = d2 < r2;
                unsigned long long m = __ballot(in);
                if (in) {
                    int pos = cnt + __popcll(m & ((1ull << lane) - 1ull));
                    if (pos < NSAMPLE) out[pos] = j;
                }
                if (!havefirst && m != 0ull) {
                    first = base + (__ffsll((long long)m) - 1);
                    havefirst = true;
                }
                cnt += __popcll(m);
            }
            if (lane >= cnt && lane < NSAMPLE) out[lane] = first;
        }
        __syncthreads();

        // ---- gather: 256 slots, slot = p*32+s ----
        if (t < TPT * NSAMPLE) {
            const int p = t >> 5;
            const int s = t & 31;
            const int gci = b * NPOINT + it0 + p;
            const int j = idx[p][s];
            const float* pj = pts + 3 * j;
            g[p][0][s] = pj[0] - new_xyz[3 * gci + 0];
            g[p][1][s] = pj[1] - new_xyz[3 * gci + 1];
            g[p][2][s] = pj[2] - new_xyz[3 * gci + 2];
            const float4* fj = (const float4*)(fts + (size_t)j * 64);
#pragma unroll
            for (int c4 = 0; c4 < 16; ++c4) {
                float4 v = fj[c4];
                g[p][3 + 4 * c4 + 0][s] = v.x;
                g[p][3 + 4 * c4 + 1][s] = v.y;
                g[p][3 + 4 * c4 + 2][s] = v.z;
                g[p][3 + 4 * c4 + 3][s] = v.w;
            }
        }
        __syncthreads();

        // ---- conv: o = t&127, quad q = t>>7 handles centers q and q+4 ----
        {
            const int o = t & 127;
            const int q = t >> 7;
            float acc0 = 0.f, acc1 = 0.f;
            const float* wr = weight + (size_t)o * NCH * NSAMPLE;
            for (int c = 0; c < NCH; ++c) {
                const float4* w4 = (const float4*)(wr + c * NSAMPLE);
#pragma unroll
                for (int s4 = 0; s4 < 8; ++s4) {
                    float4 wv = w4[s4];
                    float4 g0 = *(const float4*)&g[q][c][s4 * 4];
                    float4 g1 = *(const float4*)&g[q + 4][c][s4 * 4];
                    acc0 += g0.x * wv.x + g0.y * wv.y + g0.z * wv.z + g0.w * wv.w;
                    acc1 += g1.x * wv.x + g1.y * wv.y + g1.z * wv.z + g1.w * wv.w;
                }
            }
            float* outp = conv_out + ((size_t)b * NPOINT + it0) * NOUT;
            outp[(q    ) * NOUT + o] = acc0;
            outp[(q + 4) * NOUT + o] = acc1;
        }
        __syncthreads();   // protect g/idx before next ticket's writes
    }
}

extern "C" void kernel_launch(void* const* d_in, const int* in_sizes, int n_in,
                              void* d_out, int out_size, void* d_ws, size_t ws_size,
                              hipStream_t stream)
{
    const float* points   = (const float*)d_in[0];
    const float* features = (const float*)d_in[1];
    const float* weight   = (const float*)d_in[2];

    float* new_xyz = (float*)d_out;                              // (4,2048,3)
    float* conv    = (float*)d_out + (size_t)BATCH * NPOINT * 3; // (4,2048,128)
    int* ctl = (int*)d_ws;   // prog[4] @0, ticket @ +128B

    hipMemsetAsync(d_ws, 0, 256, stream);
    fused_kernel<<<NBLK, FPS_T, 0, stream>>>(points, features, weight,
                                             new_xyz, conv, ctl);
}

// Round 9
// 1848.006 us; speedup vs baseline: 1.5441x; 1.0816x over previous
//
#include <hip/hip_runtime.h>

#define BATCH   4
#define NPTS    8192
#define NPOINT  2048
#define NSAMPLE 32
#define NCH     67
#define NOUT    128
#define FPS_T   512
#define NWAVE   (FPS_T / 64)     // 8 waves (2 per SIMD)
#define KPT     (NPTS / FPS_T)   // 16 points per thread (setup passes)
#define NBKT    64               // 4x4x4 spatial buckets, bucket == lane
#define NFPS    4                // fps blocks (one per batch)
#define NBLK    256              // total blocks (all co-resident: <= 256 CUs)
#define TPT     8                // centers per worker ticket
#define NTICK   (BATCH * NPOINT / TPT)   // 1024 tickets
#define SENT    0xFFFFFFFFu      // NaN bit pattern from memset 0xFF

// DPP ctrl encodings (gfx9/CDNA)
#define DPP_ROW_SHR1    0x111
#define DPP_ROW_SHR2    0x112
#define DPP_ROW_SHR4    0x114
#define DPP_ROW_SHR8    0x118
#define DPP_ROW_BCAST15 0x142
#define DPP_ROW_BCAST31 0x143

#define DPP_MAX_HOP(key, ctrl)                                                 \
    {                                                                          \
        int _lo = (int)(unsigned)(key);                                        \
        int _hi = (int)(unsigned)((key) >> 32);                                \
        int _olo = __builtin_amdgcn_update_dpp(0, _lo, (ctrl), 0xF, 0xF, true);\
        int _ohi = __builtin_amdgcn_update_dpp(0, _hi, (ctrl), 0xF, 0xF, true);\
        unsigned long long _o =                                                \
            ((unsigned long long)(unsigned)_ohi << 32) | (unsigned)_olo;       \
        if (_o > (key)) (key) = _o;                                            \
    }

#define DPP_REDUCE_MAX(key)            \
    DPP_MAX_HOP(key, DPP_ROW_SHR1);    \
    DPP_MAX_HOP(key, DPP_ROW_SHR2);    \
    DPP_MAX_HOP(key, DPP_ROW_SHR4);    \
    DPP_MAX_HOP(key, DPP_ROW_SHR8);    \
    DPP_MAX_HOP(key, DPP_ROW_BCAST15); \
    DPP_MAX_HOP(key, DPP_ROW_BCAST31);

// ---------------------------------------------------------------------------
// Fused kernel, fence-free handoff. new_xyz is pre-set to 0xFF (NaN bits) by
// hipMemsetAsync; fps publishes coords with RELAXED agent-scope dword stores
// (write-through to LLC, no dirty-L2 writeback, no release fence), batched
// 16 centers at a time through an LDS ring. Workers treat the data as the
// flag: spin until the dword != 0xFFFFFFFF. Each dword is independently
// atomic, so no acquire/release ordering is needed anywhere.
// Blocks 0-3: bucketed FPS (bit-exact R7 math). Blocks 4-255: workers
// (ticket -> spin -> per-wave ball query -> gather -> conv), all on-chip.
// Co-residency: 256 blocks, 1 block/CU (LDS-bound) => no deadlock; fps never
// waits on workers.
// ---------------------------------------------------------------------------
__global__ __launch_bounds__(FPS_T) void fused_kernel(
    const float* __restrict__ points, const float* __restrict__ features,
    const float* __restrict__ weight, float* __restrict__ new_xyz,
    float* __restrict__ conv_out, int* __restrict__ ctl)
{
    __shared__ __attribute__((aligned(16))) char smem[149504];
    const int t    = threadIdx.x;
    const int lane = t & 63;
    const int w    = t >> 6;
    int* ticket = ctl;          // zeroed by hipMemsetAsync

    if (blockIdx.x < NFPS) {
        // =================== FPS path (R7 verbatim + ring publish) ==========
#pragma clang fp contract(off)
        const int b = blockIdx.x;
        const float* pts = points + (size_t)b * NPTS * 3;
        int* nxz_i = (int*)(new_xyz + (size_t)b * NPOINT * 3);

        float2* xy = (float2*)smem;                               // 65536
        float2* zd = (float2*)(smem + 65536);                     // 65536
        unsigned short* orig16 = (unsigned short*)(smem + 131072);// 16384
        unsigned long long (*key_g)[NBKT] =
            (unsigned long long (*)[NBKT])(smem + 147456);        // 1024
        int* start  = (int*)(smem + 148480);                      // 260
        int* cursor = (int*)(smem + 148744);                      // 256
        float (*bbr)[NWAVE] = (float (*)[NWAVE])(smem + 149000);  // 192
        float* cbuf = (float*)(smem + 149192);                    // 192 (ring)

        // setup: bbox
        float mnx = 1e30f, mny = 1e30f, mnz = 1e30f;
        float mxx = -1e30f, mxy = -1e30f, mxz = -1e30f;
        for (int k = 0; k < KPT; ++k) {
            const int i = k * FPS_T + t;
            float xx = pts[3 * i], yy = pts[3 * i + 1], zz = pts[3 * i + 2];
            mnx = fminf(mnx, xx); mxx = fmaxf(mxx, xx);
            mny = fminf(mny, yy); mxy = fmaxf(mxy, yy);
            mnz = fminf(mnz, zz); mxz = fmaxf(mxz, zz);
        }
#pragma unroll
        for (int off = 32; off >= 1; off >>= 1) {
            mnx = fminf(mnx, __shfl_down(mnx, off));
            mny = fminf(mny, __shfl_down(mny, off));
            mnz = fminf(mnz, __shfl_down(mnz, off));
            mxx = fmaxf(mxx, __shfl_down(mxx, off));
            mxy = fmaxf(mxy, __shfl_down(mxy, off));
            mxz = fmaxf(mxz, __shfl_down(mxz, off));
        }
        if (lane == 0) {
            bbr[0][w] = mnx; bbr[1][w] = mny; bbr[2][w] = mnz;
            bbr[3][w] = mxx; bbr[4][w] = mxy; bbr[5][w] = mxz;
        }
        if (t < NBKT) cursor[t] = 0;
        __syncthreads();
        mnx = bbr[0][0]; mny = bbr[1][0]; mnz = bbr[2][0];
        mxx = bbr[3][0]; mxy = bbr[4][0]; mxz = bbr[5][0];
#pragma unroll
        for (int q = 1; q < NWAVE; ++q) {
            mnx = fminf(mnx, bbr[0][q]); mny = fminf(mny, bbr[1][q]);
            mnz = fminf(mnz, bbr[2][q]); mxx = fmaxf(mxx, bbr[3][q]);
            mxy = fmaxf(mxy, bbr[4][q]); mxz = fmaxf(mxz, bbr[5][q]);
        }
        const float rx = mxx - mnx, ry = mxy - mny, rz = mxz - mnz;
        const float sclx = (rx > 0.f) ? 4.0f / rx : 0.f;
        const float scly = (ry > 0.f) ? 4.0f / ry : 0.f;
        const float sclz = (rz > 0.f) ? 4.0f / rz : 0.f;

        // setup: histogram
        for (int k = 0; k < KPT; ++k) {
            const int i = k * FPS_T + t;
            float xx = pts[3 * i], yy = pts[3 * i + 1], zz = pts[3 * i + 2];
            int cxi = min(3, max(0, (int)((xx - mnx) * sclx)));
            int cyi = min(3, max(0, (int)((yy - mny) * scly)));
            int czi = min(3, max(0, (int)((zz - mnz) * sclz)));
            atomicAdd(&cursor[cxi | (cyi << 2) | (czi << 4)], 1);
        }
        __syncthreads();
        if (t == 0) {
            int acc = 0;
            for (int g = 0; g < NBKT; ++g) { start[g] = acc; acc += cursor[g]; }
            start[NBKT] = acc;
        }
        __syncthreads();
        const int vs0 = start[lane];
        const int vln = start[lane + 1] - vs0;
        if (t < NBKT) cursor[t] = start[t];
        __syncthreads();

        // setup: scatter (counting sort)
        for (int k = 0; k < KPT; ++k) {
            const int i = k * FPS_T + t;
            float xx = pts[3 * i], yy = pts[3 * i + 1], zz = pts[3 * i + 2];
            int cxi = min(3, max(0, (int)((xx - mnx) * sclx)));
            int cyi = min(3, max(0, (int)((yy - mny) * scly)));
            int czi = min(3, max(0, (int)((zz - mnz) * sclz)));
            int slot = atomicAdd(&cursor[cxi | (cyi << 2) | (czi << 4)], 1);
            xy[slot] = make_float2(xx, yy);
            zd[slot] = make_float2(zz, 10000000000.0f);
            orig16[slot] = (unsigned short)i;
        }

        const float cwx = rx * 0.25f, cwy = ry * 0.25f, cwz = rz * 0.25f;
        const float bxl = mnx + (float)(lane & 3) * cwx,        bxh = bxl + cwx;
        const float byl = mny + (float)((lane >> 2) & 3) * cwy, byh = byl + cwy;
        const float bzl = mnz + (float)((lane >> 4) & 3) * cwz, bzh = bzl + cwz;
        const unsigned long long below = (1ull << lane) - 1ull;

        float cx = pts[0], cy = pts[1], cz = pts[2];
        if (t == 0) { cbuf[0] = cx; cbuf[1] = cy; cbuf[2] = cz; }  // ring slot 0
        unsigned long long kk =
            ((unsigned long long)__float_as_uint(10000000000.0f) << 32);
        __syncthreads();

        for (int it = 1; it < NPOINT; ++it) {
            const int par = it & 1;
            float ddx = fmaxf(fmaxf(bxl - cx, cx - bxh), 0.0f);
            float ddy = fmaxf(fmaxf(byl - cy, cy - byh), 0.0f);
            float ddz = fmaxf(fmaxf(bzl - cz, cz - bzh), 0.0f);
            float dmin2 = ddx * ddx + ddy * ddy + ddz * ddz;
            float ub = __uint_as_float((unsigned)(kk >> 32));
            bool scan = dmin2 < ub * 1.0001f + 1e-5f;
            unsigned long long m = __ballot(scan);

            const int rank = (int)__popcll(m & below);
            const bool mine = scan && ((rank & (NWAVE - 1)) == w);
            unsigned long long mw = __ballot(mine);

            while (mw) {
                const int g = __ffsll((long long)mw) - 1;
                mw &= mw - 1;
                const int s0 = __builtin_amdgcn_readlane(vs0, g);
                const int ln = __builtin_amdgcn_readlane(vln, g);
                unsigned long long bk = 0;
                for (int jo = lane; jo < ln; jo += 64) {
                    const int j = s0 + jo;
                    float2 vxy = xy[j];
                    float2 vzd = zd[j];
                    float dx = vxy.x - cx;
                    float dy = vxy.y - cy;
                    float dz = vzd.x - cz;
                    float d  = ((dx * dx) + (dy * dy)) + (dz * dz);
                    float nd = fminf(vzd.y, d);
                    zd[j].y = nd;
                    unsigned long long kkey =
                        ((unsigned long long)__float_as_uint(nd) << 32)
                      | ((unsigned)(8191 - (int)orig16[j]) << 13)
                      | (unsigned)j;
                    if (kkey > bk) bk = kkey;
                }
                DPP_REDUCE_MAX(bk);
                if (lane == 63) key_g[par][g] = bk;
            }
            __syncthreads();

            if (scan) kk = key_g[par][lane];
            unsigned long long rr = kk;
            DPP_REDUCE_MAX(rr);
            const unsigned rlo =
                (unsigned)__builtin_amdgcn_readlane((int)(unsigned)rr, 63);
            const int slot = (int)(rlo & 0x1FFFu);
            float2 wxy = xy[slot];
            float2 wzd = zd[slot];
            cx = wxy.x; cy = wxy.y; cz = wzd.x;
            // bank the center into the LDS ring (slot = it mod 16)
            if (t == 0) {
                const int rs = (it & 15) * 3;
                cbuf[rs] = cx; cbuf[rs + 1] = cy; cbuf[rs + 2] = cz;
            }
            // every 16 iters: lanes 0-47 of wave 0 flush 16 centers with
            // relaxed agent-scope (sc1, write-through) stores — no fence,
            // no L2 writeback; vmcnt drains at a later barrier off-path.
            if (((it & 15) == 15) && t < 48) {
                const int base3 = (it & ~15) * 3;
                __hip_atomic_store(&nxz_i[base3 + t],
                                   __float_as_int(cbuf[t]),
                                   __ATOMIC_RELAXED, __HIP_MEMORY_SCOPE_AGENT);
            }
        }
        return;
    }

    // ======================= worker path ===================================
    float (*g)[NCH][NSAMPLE] = (float (*)[NCH][NSAMPLE])smem;  // 68608 B
    int (*idx)[NSAMPLE] = (int (*)[NSAMPLE])(smem + 68608);    //  1024 B
    float (*cc)[4] = (float (*)[4])(smem + 69632);             //   128 B
    int* tk_s = (int*)(smem + 69760);

    const int* nxz_all = (const int*)new_xyz;

    for (;;) {
        if (t == 0) *tk_s = atomicAdd(ticket, 1);
        __syncthreads();
        const int T = *tk_s;
        __syncthreads();
        if (T >= NTICK) break;
        const int b   = T & 3;
        const int it0 = (T >> 2) * TPT;

        const float* pts = points + (size_t)b * NPTS * 3;
        const float* fts = features + (size_t)b * NPTS * 64;
        const int gci = b * NPOINT + it0 + w;   // this wave's center

        // ---- spin until this center's 3 coords are published (data=flag) --
        float cxw = 0.f, cyw = 0.f, czw = 0.f;
        if (lane == 0) {
            unsigned v;
            do {
                v = (unsigned)__hip_atomic_load(&nxz_all[3 * gci + 0],
                        __ATOMIC_RELAXED, __HIP_MEMORY_SCOPE_AGENT);
                if (v != SENT) break;
                __builtin_amdgcn_s_sleep(2);
            } while (true);
            cxw = __uint_as_float(v);
            do {
                v = (unsigned)__hip_atomic_load(&nxz_all[3 * gci + 1],
                        __ATOMIC_RELAXED, __HIP_MEMORY_SCOPE_AGENT);
                if (v != SENT) break;
                __builtin_amdgcn_s_sleep(2);
            } while (true);
            cyw = __uint_as_float(v);
            do {
                v = (unsigned)__hip_atomic_load(&nxz_all[3 * gci + 2],
                        __ATOMIC_RELAXED, __HIP_MEMORY_SCOPE_AGENT);
                if (v != SENT) break;
                __builtin_amdgcn_s_sleep(2);
            } while (true);
            czw = __uint_as_float(v);
        }
        cxw = __shfl(cxw, 0); cyw = __shfl(cyw, 0); czw = __shfl(czw, 0);
        if (lane == 0) { cc[w][0] = cxw; cc[w][1] = cyw; cc[w][2] = czw; }

        // ---- ball query: wave w handles center it0+w (bit-exact) ----------
        {
#pragma clang fp contract(off)
            const float r2 = (float)(0.2 * 0.2);
            int* out = idx[w];
            int cnt = 0, first = 0;
            bool havefirst = false;
            for (int base = 0; base < NPTS && cnt < NSAMPLE; base += 64) {
                const int j = base + lane;
                float dx = pts[3 * j + 0] - cxw;
                float dy = pts[3 * j + 1] - cyw;
                float dz = pts[3 * j + 2] - czw;
                float d2 = ((dx * dx) + (dy * dy)) + (dz * dz);
                const bool in = d2 < r2;
                unsigned long long m = __ballot(in);
                if (in) {
                    int pos = cnt + __popcll(m & ((1ull << lane) - 1ull));
                    if (pos < NSAMPLE) out[pos] = j;
                }
                if (!havefirst && m != 0ull) {
                    first = base + (__ffsll((long long)m) - 1);
                    havefirst = true;
                }
                cnt += __popcll(m);
            }
            if (lane >= cnt && lane < NSAMPLE) out[lane] = first;
        }
        __syncthreads();

        // ---- gather: 256 slots, slot = p*32+s ----
        if (t < TPT * NSAMPLE) {
            const int p = t >> 5;
            const int s = t & 31;
            const int j = idx[p][s];
            const float* pj = pts + 3 * j;
            g[p][0][s] = pj[0] - cc[p][0];
            g[p][1][s] = pj[1] - cc[p][1];
            g[p][2][s] = pj[2] - cc[p][2];
            const float4* fj = (const float4*)(fts + (size_t)j * 64);
#pragma unroll
            for (int c4 = 0; c4 < 16; ++c4) {
                float4 v = fj[c4];
                g[p][3 + 4 * c4 + 0][s] = v.x;
                g[p][3 + 4 * c4 + 1][s] = v.y;
                g[p][3 + 4 * c4 + 2][s] = v.z;
                g[p][3 + 4 * c4 + 3][s] = v.w;
            }
        }
        __syncthreads();

        // ---- conv: o = t&127, quad q = t>>7 handles centers q and q+4 ----
        {
            const int o = t & 127;
            const int q = t >> 7;
            float acc0 = 0.f, acc1 = 0.f;
            const float* wr = weight + (size_t)o * NCH * NSAMPLE;
            for (int c = 0; c < NCH; ++c) {
                const float4* w4 = (const float4*)(wr + c * NSAMPLE);
#pragma unroll
                for (int s4 = 0; s4 < 8; ++s4) {
                    float4 wv = w4[s4];
                    float4 g0 = *(const float4*)&g[q][c][s4 * 4];
                    float4 g1 = *(const float4*)&g[q + 4][c][s4 * 4];
                    acc0 += g0.x * wv.x + g0.y * wv.y + g0.z * wv.z + g0.w * wv.w;
                    acc1 += g1.x * wv.x + g1.y * wv.y + g1.z * wv.z + g1.w * wv.w;
                }
            }
            float* outp = conv_out + ((size_t)b * NPOINT + it0) * NOUT;
            outp[(q    ) * NOUT + o] = acc0;
            outp[(q + 4) * NOUT + o] = acc1;
        }
        __syncthreads();   // protect g/idx/cc before next ticket's writes
    }
}

extern "C" void kernel_launch(void* const* d_in, const int* in_sizes, int n_in,
                              void* d_out, int out_size, void* d_ws, size_t ws_size,
                              hipStream_t stream)
{
    const float* points   = (const float*)d_in[0];
    const float* features = (const float*)d_in[1];
    const float* weight   = (const float*)d_in[2];

    float* new_xyz = (float*)d_out;                              // (4,2048,3)
    float* conv    = (float*)d_out + (size_t)BATCH * NPOINT * 3; // (4,2048,128)
    int* ctl = (int*)d_ws;   // ticket counter

    hipMemsetAsync(d_ws, 0, 64, stream);
    // seed new_xyz with 0xFFFFFFFF sentinel (NaN bits): data doubles as flag
    hipMemsetAsync(new_xyz, 0xFF, (size_t)BATCH * NPOINT * 3 * 4, stream);
    fused_kernel<<<NBLK, FPS_T, 0, stream>>>(points, features, weight,
                                             new_xyz, conv, ctl);
}